// Round 3
// baseline (1206.990 us; speedup 1.0000x reference)
//
#include <hip/hip_runtime.h>
#include <stdint.h>

typedef unsigned short u16;
typedef short short8 __attribute__((ext_vector_type(8)));
typedef short short4v __attribute__((ext_vector_type(4)));
typedef float f32x4 __attribute__((ext_vector_type(4)));

#define DEV static __device__ __forceinline__

DEV u16 f2bf(float x) {
    union { float f; uint32_t u; } v; v.f = x;
    uint32_t r = v.u + 0x7FFFu + ((v.u >> 16) & 1u);   // RNE
    return (u16)(r >> 16);
}
DEV float bf2f(u16 h) {
    union { uint32_t u; float f; } v; v.u = ((uint32_t)h) << 16;
    return v.f;
}

// async global->LDS, 16B per lane; LDS dest is wave-uniform base + lane*16 (guide m104)
DEV void gload_lds16(const u16* g, u16* l) {
    __builtin_amdgcn_global_load_lds(
        (__attribute__((address_space(1))) void*)g,
        (__attribute__((address_space(3))) void*)l, 16, 0, 0);
}

enum { F_RELU = 1, F_CSKIP = 4, F_CKLIM = 8, F_BIAS0Z = 16, F_SPLITK = 32 };

// ---------------------------------------------------------------------------
// m97-structure 128x128 GEMM: C = A[M,K] @ B^T, B stored [N,K] bf16.
// blockIdx.z: batch (strides sA/sB/sC in elements) OR K-chunk (F_SPLITK:
// sA/sB = chunk offset along K, sC = output-buffer stride; K = chunk size).
// ---------------------------------------------------------------------------
__global__ __launch_bounds__(256, 2)
void gemm_bt(const u16* __restrict__ A, const u16* __restrict__ B,
             float* __restrict__ Cf, u16* __restrict__ Cb,
             const float* __restrict__ bias,
             int M, int N, int K, int lda, int ldb, int ldc,
             long long sA, long long sB, long long sC,
             float scale, int flags)
{
    const int tm = blockIdx.x, tn = blockIdx.y, bz = blockIdx.z;
    if ((flags & F_CSKIP) && tn > tm) return;
    A += (long long)bz * sA;
    B += (long long)bz * sB;
    const long long coff = (long long)bz * sC;

    __shared__ u16 As[128 * 32];
    __shared__ u16 Bs[128 * 32];

    const int tid = threadIdx.x;
    const int lane = tid & 63, w = tid >> 6;
    const int wr = w >> 1, wc = w & 1;
    const int l15 = lane & 15, l4 = lane >> 4;

    f32x4 acc[4][4];
    const f32x4 z4 = {0.f, 0.f, 0.f, 0.f};
#pragma unroll
    for (int m = 0; m < 4; ++m)
#pragma unroll
        for (int n = 0; n < 4; ++n) acc[m][n] = z4;

    int kend = K;
    if (flags & F_CKLIM) { int ke = (tm + 1) * 128; if (ke < kend) kend = ke; }

    const u16* Abase = A + (long long)tm * 128 * lda;
    const u16* Bbase = B + (long long)tn * 128 * ldb;

    for (int k0 = 0; k0 < kend; k0 += 32) {
#pragma unroll
        for (int i = 0; i < 2; ++i) {
            const int e0 = (i * 4 + w) * 512;
            const int e  = e0 + lane * 8;
            const int row = e >> 5, col = e & 31;
            gload_lds16(Abase + (long long)row * lda + (k0 + col), (u16*)As + e0);
            gload_lds16(Bbase + (long long)row * ldb + (k0 + col), (u16*)Bs + e0);
        }
        __syncthreads();

        short8 af[4], bfr[4];
#pragma unroll
        for (int m = 0; m < 4; ++m)
            af[m] = *(const short8*)&As[(wr * 64 + m * 16 + l15) * 32 + l4 * 8];
#pragma unroll
        for (int n = 0; n < 4; ++n)
            bfr[n] = *(const short8*)&Bs[(wc * 64 + n * 16 + l15) * 32 + l4 * 8];
#pragma unroll
        for (int m = 0; m < 4; ++m)
#pragma unroll
            for (int n = 0; n < 4; ++n)
                acc[m][n] = __builtin_amdgcn_mfma_f32_16x16x32_bf16(af[m], bfr[n], acc[m][n], 0, 0, 0);
        __syncthreads();
    }

    // C/D layout: col = lane&15, row = (lane>>4)*4 + reg (verified m89/m91)
#pragma unroll
    for (int n = 0; n < 4; ++n) {
        const int c = tn * 128 + wc * 64 + n * 16 + l15;
        const float bv = (bias && (!(flags & F_BIAS0Z) || bz == 0)) ? bias[c] : 0.0f;
#pragma unroll
        for (int m = 0; m < 4; ++m) {
            const int r0 = tm * 128 + wr * 64 + m * 16 + l4 * 4;
#pragma unroll
            for (int j = 0; j < 4; ++j) {
                float v = acc[m][n][j] * scale + bv;
                if (flags & F_RELU) v = fmaxf(v, 0.0f);
                const long long off = coff + (long long)(r0 + j) * ldc + c;
                if (Cf) Cf[off] = v;
                if (Cb) Cb[off] = f2bf(v);
            }
        }
    }
}

// ---------------------------------------------------------------------------
// batched weight transpose: all weights, both layers, one dispatch.
// in [R,C] f32 -> out [C,R] bf16 (scaled). grid (12288, NL), block (32,8).
// ---------------------------------------------------------------------------
__global__ void transpose_all(const float* __restrict__ wq, const float* __restrict__ wk,
                              const float* __restrict__ wv, const float* __restrict__ wo,
                              const float* __restrict__ wup, const float* __restrict__ wdown,
                              u16* __restrict__ wqkv_t, u16* __restrict__ wo_t,
                              u16* __restrict__ wup_t, u16* __restrict__ wdown_t,
                              float qscale)
{
    const int gid = blockIdx.x, l = blockIdx.y;
    const float* in;
    u16* out;
    int R, C, gx, gy;
    float scale = 1.0f;

    if (gid < 4096) {                       // wq|wk|wv|wo (1024x1024 each)
        const int seg = gid >> 10, widx = gid & 1023;
        R = 1024; C = 1024; gx = widx & 31; gy = widx >> 5;
        if (seg == 0)      { in = wq + (size_t)l * 1048576; out = wqkv_t + (size_t)l * 3145728;            scale = qscale; }
        else if (seg == 1) { in = wk + (size_t)l * 1048576; out = wqkv_t + (size_t)l * 3145728 + 1048576; }
        else if (seg == 2) { in = wv + (size_t)l * 1048576; out = wqkv_t + (size_t)l * 3145728 + 2097152; }
        else               { in = wo + (size_t)l * 1048576; out = wo_t   + (size_t)l * 1048576; }
    } else if (gid < 8192) {                // wup [1024,4096] -> [4096,1024]
        const int widx = gid - 4096;
        R = 1024; C = 4096; gx = widx & 127; gy = widx >> 7;
        in = wup + (size_t)l * 4194304; out = wup_t + (size_t)l * 4194304;
    } else {                                // wdown [4096,1024] -> [1024,4096]
        const int widx = gid - 8192;
        R = 4096; C = 1024; gx = widx & 31; gy = widx >> 5;
        in = wdown + (size_t)l * 4194304; out = wdown_t + (size_t)l * 4194304;
    }

    __shared__ float tile[32][33];
    const int tx = threadIdx.x, ty = threadIdx.y;
#pragma unroll
    for (int i = 0; i < 4; ++i)
        tile[ty + i * 8][tx] = in[(long long)(gy * 32 + ty + i * 8) * C + gx * 32 + tx];
    __syncthreads();
#pragma unroll
    for (int i = 0; i < 4; ++i)
        out[(long long)(gx * 32 + ty + i * 8) * R + gy * 32 + tx] = f2bf(tile[tx][ty + i * 8] * scale);
}

// in [R,C] bf16 (row stride ldin) -> out [C,R] bf16, batched via z
__global__ void transpose_b2b(const u16* __restrict__ in, u16* __restrict__ out,
                              int R, int C, int ldin, long long sIn, long long sOut)
{
    __shared__ u16 tile[32][34];
    in  += (long long)blockIdx.z * sIn;
    out += (long long)blockIdx.z * sOut;
    const int tx = threadIdx.x, ty = threadIdx.y;
    const int gx = blockIdx.x, gy = blockIdx.y;
#pragma unroll
    for (int i = 0; i < 4; ++i)
        tile[ty + i * 8][tx] = in[(long long)(gy * 32 + ty + i * 8) * ldin + gx * 32 + tx];
    __syncthreads();
#pragma unroll
    for (int i = 0; i < 4; ++i)
        out[(long long)(gx * 32 + ty + i * 8) * R + gy * 32 + tx] = tile[tx][ty + i * 8];
}

__global__ __launch_bounds__(256)
void embed_kernel(const int* __restrict__ x, const float* __restrict__ emb,
                  const float* __restrict__ pos, float* __restrict__ h32, u16* __restrict__ hbf)
{
    const long long row = blockIdx.x;
    const int t = (int)(row & 2047);
    const int idx = x[row];
    const int tid = threadIdx.x;
    const float4 e = ((const float4*)(emb + (long long)idx * 1024))[tid];
    const float4 p = ((const float4*)(pos + (long long)t * 1024))[tid];
    float y0 = e.x + p.x, y1 = e.y + p.y, y2 = e.z + p.z, y3 = e.w + p.w;
    float4 o; o.x = y0; o.y = y1; o.z = y2; o.w = y3;
    ((float4*)(h32 + row * 1024))[tid] = o;
    short4v ob = { (short)f2bf(y0), (short)f2bf(y1), (short)f2bf(y2), (short)f2bf(y3) };
    *(short4v*)(hbf + row * 1024 + tid * 4) = ob;
}

// o = LN(a + b [+ c])*gamma + beta over D=1024; c may be nullptr.
__global__ __launch_bounds__(256)
void ln_kernel(const float* __restrict__ a, const float* __restrict__ b,
               const float* __restrict__ c,
               const float* __restrict__ gamma, const float* __restrict__ beta,
               float* __restrict__ o32, u16* __restrict__ obf)
{
    const long long row = blockIdx.x;
    const int tid = threadIdx.x, lane = tid & 63, w = tid >> 6;
    const float4 xa = ((const float4*)(a + row * 1024))[tid];
    const float4 xb = ((const float4*)(b + row * 1024))[tid];
    float x0 = xa.x + xb.x, x1 = xa.y + xb.y, x2 = xa.z + xb.z, x3 = xa.w + xb.w;
    if (c) {
        const float4 xc = ((const float4*)(c + row * 1024))[tid];
        x0 += xc.x; x1 += xc.y; x2 += xc.z; x3 += xc.w;
    }
    float s = x0 + x1 + x2 + x3;
    float q = x0 * x0 + x1 * x1 + x2 * x2 + x3 * x3;
#pragma unroll
    for (int o = 32; o; o >>= 1) { s += __shfl_xor(s, o, 64); q += __shfl_xor(q, o, 64); }
    __shared__ float red[8];
    if (lane == 0) { red[w] = s; red[4 + w] = q; }
    __syncthreads();
    s = red[0] + red[1] + red[2] + red[3];
    q = red[4] + red[5] + red[6] + red[7];
    const float mu = s * (1.0f / 1024.0f);
    const float var = q * (1.0f / 1024.0f) - mu * mu;
    const float rs = rsqrtf(var + 1e-5f);
    const float4 g  = ((const float4*)gamma)[tid];
    const float4 be = ((const float4*)beta)[tid];
    float y0 = (x0 - mu) * rs * g.x + be.x;
    float y1 = (x1 - mu) * rs * g.y + be.y;
    float y2 = (x2 - mu) * rs * g.z + be.z;
    float y3 = (x3 - mu) * rs * g.w + be.w;
    float4 o; o.x = y0; o.y = y1; o.z = y2; o.w = y3;
    ((float4*)(o32 + row * 1024))[tid] = o;
    short4v ob = { (short)f2bf(y0), (short)f2bf(y1), (short)f2bf(y2), (short)f2bf(y3) };
    *(short4v*)(obf + row * 1024 + tid * 4) = ob;
}

// in-place causal softmax on bf16 S rows of length 2048; processes only the
// 128-aligned causal prefix (PV's F_CKLIM never reads beyond it).
__global__ __launch_bounds__(256)
void softmax_causal(u16* __restrict__ SP)
{
    const long long row = blockIdx.x;
    const int t = (int)(row & 2047);
    const int limit = ((t >> 7) + 1) << 7;          // 128-aligned prefix
    u16* p = SP + row * 2048;
    const int tid = threadIdx.x, lane = tid & 63, w = tid >> 6;
    const bool act = (tid * 8) < limit;

    short8 v = {0, 0, 0, 0, 0, 0, 0, 0};
    if (act) v = *(const short8*)&p[tid * 8];
    float x[8];
#pragma unroll
    for (int j = 0; j < 8; ++j) {
        const int cc = tid * 8 + j;
        x[j] = (act && cc <= t) ? bf2f((u16)v[j]) : -1e30f;
    }
    float mx = x[0];
#pragma unroll
    for (int j = 1; j < 8; ++j) mx = fmaxf(mx, x[j]);
#pragma unroll
    for (int o = 32; o; o >>= 1) mx = fmaxf(mx, __shfl_xor(mx, o, 64));
    __shared__ float red[8];
    if (lane == 0) red[w] = mx;
    __syncthreads();
    mx = fmaxf(fmaxf(red[0], red[1]), fmaxf(red[2], red[3]));

    float s = 0.f;
#pragma unroll
    for (int j = 0; j < 8; ++j) {
        const float e = (act && tid * 8 + j <= t) ? exp2f((x[j] - mx) * 1.44269504f) : 0.f;
        x[j] = e; s += e;
    }
#pragma unroll
    for (int o = 32; o; o >>= 1) s += __shfl_xor(s, o, 64);
    if (lane == 0) red[4 + w] = s;
    __syncthreads();
    s = red[4] + red[5] + red[6] + red[7];
    const float inv = 1.0f / s;

    if (act) {
        short8 ov;
#pragma unroll
        for (int j = 0; j < 8; ++j) ov[j] = (short)f2bf(x[j] * inv);
        *(short8*)&p[tid * 8] = ov;
    }
}

extern "C" void kernel_launch(void* const* d_in, const int* in_sizes, int n_in,
                              void* d_out, int out_size, void* d_ws, size_t ws_size,
                              hipStream_t stream)
{
    (void)in_sizes; (void)n_in; (void)out_size; (void)ws_size;
    const int Dd = 1024, T_ = 2048, B_ = 4, NLl = 2, M = B_ * T_;
    const float inv_sqrt_d = 0.03125f;

    const int*   x     = (const int*)  d_in[0];
    const float* emb   = (const float*)d_in[1];
    const float* pos   = (const float*)d_in[2];
    const float* wq    = (const float*)d_in[3];
    const float* wk    = (const float*)d_in[4];
    const float* wv    = (const float*)d_in[5];
    const float* wo    = (const float*)d_in[6];
    const float* wup   = (const float*)d_in[7];
    const float* bup   = (const float*)d_in[8];
    const float* wdown = (const float*)d_in[9];
    const float* bdown = (const float*)d_in[10];
    const float* ga    = (const float*)d_in[11];
    const float* ba    = (const float*)d_in[12];
    const float* gm    = (const float*)d_in[13];
    const float* bm    = (const float*)d_in[14];

    char* ws = (char*)d_ws;
    size_t off = 0;
    auto alloc = [&](size_t bytes) -> void* {
        void* p = ws + off; off += (bytes + 255) & ~(size_t)255; return p;
    };
    float* h32   = (float*)alloc((size_t)M * Dd * 4);
    u16*   hbf   = (u16*)  alloc((size_t)M * Dd * 2);
    float* za    = (float*)alloc((size_t)M * Dd * 4);        // split-K partial 0
    float* zb    = (float*)alloc((size_t)M * Dd * 4);        // split-K partial 1
    u16*   qkv   = (u16*)  alloc((size_t)M * 3072 * 2);      // [M,3072] q|k|v
    u16*   abf   = (u16*)  alloc((size_t)M * Dd * 2);        // attn out
    u16*   vtbf  = (u16*)  alloc((size_t)M * Dd * 2);        // per-batch [D,T]
    u16*   SP    = (u16*)  alloc((size_t)B_ * T_ * T_ * 2);
    u16*   ubf   = (u16*)  alloc((size_t)M * 4096 * 2);      // MLP hidden
    u16*   wqkv_t  = (u16*)alloc((size_t)NLl * 3072 * 1024 * 2);
    u16*   wo_t    = (u16*)alloc((size_t)NLl * 1024 * 1024 * 2);
    u16*   wup_t   = (u16*)alloc((size_t)NLl * 4096 * 1024 * 2);
    u16*   wdown_t = (u16*)alloc((size_t)NLl * 1024 * 4096 * 2);
    const long long zstride = (long long)M * Dd;             // za -> zb

    dim3 blk(256);
    dim3 tblk(32, 8);

    // all weight transposes, both layers, one dispatch
    transpose_all<<<dim3(12288, NLl), tblk, 0, stream>>>(wq, wk, wv, wo, wup, wdown,
        wqkv_t, wo_t, wup_t, wdown_t, inv_sqrt_d);

    embed_kernel<<<M, blk, 0, stream>>>(x, emb, pos, h32, hbf);

    for (int l = 0; l < NLl; ++l) {
        u16* wqkv_l  = wqkv_t  + (size_t)l * 3072 * 1024;
        u16* wo_l    = wo_t    + (size_t)l * 1024 * 1024;
        u16* wup_l   = wup_t   + (size_t)l * 4096 * 1024;
        u16* wdown_l = wdown_t + (size_t)l * 1024 * 4096;

        // fused QKV: [M,1024] @ [3072,1024]^T -> [M,3072]   (1536 blocks, 6/CU)
        gemm_bt<<<dim3(64, 24, 1), blk, 0, stream>>>(hbf, wqkv_l, nullptr, qkv, nullptr,
            M, 3072, 1024, 1024, 1024, 3072, 0, 0, 0, 1.0f, 0);

        // V^T per batch: [T,D] (stride 3072) -> [D,T]
        transpose_b2b<<<dim3(32, 64, 4), tblk, 0, stream>>>(qkv + 2048, vtbf, 2048, 1024,
            3072, (long long)T_ * 3072, (long long)Dd * T_);

        // S = Q K^T (causal tile skip)
        gemm_bt<<<dim3(16, 16, 4), blk, 0, stream>>>(qkv, qkv + 1024, nullptr, SP, nullptr,
            2048, 2048, 1024, 3072, 3072, 2048,
            (long long)T_ * 3072, (long long)T_ * 3072, (long long)T_ * T_, 1.0f, F_CSKIP);

        softmax_causal<<<B_ * T_, blk, 0, stream>>>(SP);

        // attn = P V (K-limit per row tile)
        gemm_bt<<<dim3(16, 8, 4), blk, 0, stream>>>(SP, vtbf, nullptr, abf, nullptr,
            2048, 1024, 2048, 2048, 2048, 1024,
            (long long)T_ * T_, (long long)Dd * T_, (long long)T_ * Dd, 1.0f, F_CKLIM);

        // proj = attn @ wo, split-K x2 in one dispatch (1024 blocks, 4/CU)
        gemm_bt<<<dim3(64, 8, 2), blk, 0, stream>>>(abf, wo_l, za, nullptr, nullptr,
            M, 1024, 512, 1024, 1024, 1024, 512, 512, zstride, 1.0f, F_SPLITK);

        // h = LN(residual + za + zb)
        ln_kernel<<<M, blk, 0, stream>>>(h32, za, zb,
            ga + (size_t)l * Dd, ba + (size_t)l * Dd, h32, hbf);

        // MLP up: [M,1024] @ [4096,1024]^T + bias, relu   (2048 blocks, 8/CU)
        gemm_bt<<<dim3(64, 32, 1), blk, 0, stream>>>(hbf, wup_l, nullptr, ubf,
            bup + (size_t)l * 4096,
            M, 4096, 1024, 1024, 1024, 4096, 0, 0, 0, 1.0f, F_RELU);

        // MLP down: [M,4096] @ [1024,4096]^T + bias, split-K x2 (1024 blocks)
        gemm_bt<<<dim3(64, 8, 2), blk, 0, stream>>>(ubf, wdown_l, za, nullptr,
            bdown + (size_t)l * Dd,
            M, 1024, 2048, 4096, 4096, 1024, 2048, 2048, zstride, 1.0f, F_SPLITK | F_BIAS0Z);

        // h = LN(h + za + zb); final layer writes d_out (f32)
        float* lnout = (l == NLl - 1) ? (float*)d_out : h32;
        ln_kernel<<<M, blk, 0, stream>>>(h32, za, zb,
            gm + (size_t)l * Dd, bm + (size_t)l * Dd, lnout, hbf);
    }
}